// Round 3
// baseline (14937.241 us; speedup 1.0000x reference)
//
#include <hip/hip_runtime.h>
#include <hip/hip_bf16.h>

// SenseMemAct: sense Linear -> nBRC scan (L=1024) -> actor Linear -> softmax
// Inputs AND output: float32 (per reference file; round-1 NaN proved inputs f32,
// round-2 stub-identical error proved output is read as f32).
//
//  - k_sense:  inputs[t][b][128] = x @ W_sense + b_sense  (f32 in, bf16 out)
//  - k_pack:   W_mm / W_im (f32) repacked into bf16 MFMA B-fragment order
//  - k_main:   persistent kernel, 256 WGs x 256 thr. 4 groups x 16 batches,
//              64 members/group x 16 h-cols. W_mm frags register-resident.
//              Per-step per-group barrier: monotonic device-scope counter.
//  - k_final:  + b_act, softmax over DEC=3, write f32 out [B,L,3]

#define B_TOT 64
#define L_SEQ 1024
#define N_IN 64
#define INSZ 128
#define MEM 1024
#define DEC 3

#define NGROUP 4
#define BG 16
#define NMEM 64

typedef __hip_bfloat16 bf16;
typedef short bf16x8 __attribute__((ext_vector_type(8)));
typedef float f32x4 __attribute__((ext_vector_type(4)));

// ---- workspace layout (bytes) ----
#define OFF_INPUTS 0
#define SZ_INPUTS  (L_SEQ * 64 * INSZ * 2)                 // 16 MB (bf16)
#define OFF_WMM    (OFF_INPUTS + SZ_INPUTS)
#define SZ_WMM     (128 * 32 * 64 * 8 * 2)                 // 4 MB
#define OFF_WIM    (OFF_WMM + SZ_WMM)
#define SZ_WIM     (192 * 4 * 64 * 8 * 2)                  // 0.75 MB
#define OFF_HBUF   (OFF_WIM + SZ_WIM)
#define SZ_HBUF    (2 * NGROUP * BG * MEM * 2)             // 256 KB
#define OFF_ACC    (OFF_HBUF + SZ_HBUF)
#define SZ_ACC     (L_SEQ * B_TOT * DEC * 4)               // 768 KB
#define OFF_CTR    (OFF_ACC + SZ_ACC)
#define SZ_CTR     (NGROUP * 64 * 4)

// ---------------- sense: inputs = x @ W_sense + b_sense ----------------
// one block per timestep t; 256 threads; thread = (j = tid&127, bhalf = tid>>7)
__global__ void k_sense(const float* __restrict__ x, const float* __restrict__ Ws,
                        const float* __restrict__ bs, bf16* __restrict__ inputs) {
    int t = blockIdx.x;
    int tid = threadIdx.x;
    __shared__ float xls[64][64];
    __shared__ float wls[64][128];
    for (int idx = tid; idx < 64 * 64; idx += 256) {
        int b = idx >> 6, k = idx & 63;
        xls[b][k] = x[((size_t)b * L_SEQ + t) * N_IN + k];
    }
    for (int idx = tid; idx < 64 * 128; idx += 256) {
        int k = idx >> 7, j = idx & 127;
        wls[k][j] = Ws[k * INSZ + j];
    }
    __syncthreads();
    int j = tid & 127;
    int bh = tid >> 7;
    float bj = bs[j];
    for (int bi = 0; bi < 32; ++bi) {
        int b = bh * 32 + bi;
        float acc = bj;
#pragma unroll
        for (int k = 0; k < 64; ++k) acc += xls[b][k] * wls[k][j];
        inputs[((size_t)t * 64 + b) * INSZ + j] = (bf16)acc;
    }
}

// ---------------- pack weights into bf16 MFMA B-fragment order ----------------
// frag element (ct, kb, lane, j): n = ct*16 + (lane&15); k = kb*32 + (lane>>4)*8 + j
__global__ void k_pack(const float* __restrict__ Wmm, const float* __restrict__ Wim,
                       bf16* __restrict__ pmm, bf16* __restrict__ pim) {
    int idx = blockIdx.x * 256 + threadIdx.x;
    const int NMMF = 128 * 32 * 64 * 8;  // 2097152
    if (idx < NMMF) {
        int j = idx & 7, lane = (idx >> 3) & 63, kb = (idx >> 9) & 31, ct = idx >> 14;
        int n = ct * 16 + (lane & 15);
        int k = kb * 32 + ((lane >> 4) << 3) + j;
        pmm[idx] = (bf16)Wmm[(size_t)k * 2048 + n];
    } else {
        int idx2 = idx - NMMF;
        if (idx2 < 192 * 4 * 64 * 8) {
            int j = idx2 & 7, lane = (idx2 >> 3) & 63, kb = (idx2 >> 9) & 3, ct = idx2 >> 11;
            int n = ct * 16 + (lane & 15);
            int k = kb * 32 + ((lane >> 4) << 3) + j;
            pim[idx2] = (bf16)Wim[(size_t)k * 3072 + n];
        }
    }
}

// ---------------- persistent recurrent kernel ----------------
__launch_bounds__(256, 1)
__global__ void k_main(const bf16* __restrict__ inputs, const bf16* __restrict__ pmm,
                       const bf16* __restrict__ pim, const float* __restrict__ Wact,
                       bf16* __restrict__ hbuf, float* __restrict__ accout,
                       unsigned int* __restrict__ ctr) {
    const int g = blockIdx.x & 3;       // group (16 batches)
    const int m = blockIdx.x >> 2;      // member (16 h-cols)
    const int tid = (int)threadIdx.x;
    const int wave = tid >> 6;
    const int lane = tid & 63;
    const int r16 = lane & 15;          // A-row / B-col within tile
    const int q = lane >> 4;            // quad
    const int cl = tid & 15;            // elementwise local col
    const int bloc = tid >> 4;          // elementwise local batch

    __shared__ bf16 Hlds[16][1032];     // stride 1032: word stride 516 == 4 (mod 32)
    __shared__ float ilds[2][3][16][16];
    __shared__ float mlds[4][16][16];
    __shared__ float ownh[16][16];

    // register-resident W_mm fragments: waves 0,1 -> ct=m (m_a); waves 2,3 -> ct=64+m (m_c)
    bf16x8 wb[16];
    {
        int ct = (wave < 2) ? m : 64 + m;
        int kh = wave & 1;
#pragma unroll
        for (int i = 0; i < 16; ++i) {
            int kb = kh * 16 + i;
            wb[i] = *(const bf16x8*)(pmm + (((size_t)ct * 32 + kb) * 64 + lane) * 8);
        }
    }
    // W_im fragments: wave w in {0,1,2} handles i_a / i_c / i_o  (ct2 = w*64 + m)
    bf16x8 wi[4];
    if (wave < 3) {
        int ct2 = wave * 64 + m;
#pragma unroll
        for (int kb2 = 0; kb2 < 4; ++kb2)
            wi[kb2] = *(const bf16x8*)(pim + (((size_t)ct2 * 4 + kb2) * 64 + lane) * 8);
    }
    // actor weights for this thread's h-column (f32)
    float wa0, wa1, wa2;
    {
        int col = m * 16 + cl;
        wa0 = Wact[col * 3 + 0];
        wa1 = Wact[col * 3 + 1];
        wa2 = Wact[col * 3 + 2];
    }
    ownh[bloc][cl] = 0.f;

    auto comp_iacc = [&](int t) -> f32x4 {
        f32x4 a = {0.f, 0.f, 0.f, 0.f};
        if (wave < 3) {
#pragma unroll
            for (int kb2 = 0; kb2 < 4; ++kb2) {
                bf16x8 af = *(const bf16x8*)(inputs +
                    ((size_t)t * 64 + g * 16 + r16) * INSZ + kb2 * 32 + q * 8);
                a = __builtin_amdgcn_mfma_f32_16x16x32_bf16(af, wi[kb2], a, 0, 0, 0);
            }
        }
        return a;
    };

    f32x4 iacc = comp_iacc(0);
    unsigned int* myctr = ctr + g * 64;
    int spin_budget = 1 << 24;   // converts any barrier bug into wrong-answer, not a hang

#pragma clang loop unroll(disable)
    for (int t = 0; t < L_SEQ; ++t) {
        // deposit this step's input-projection tiles
        if (wave < 3) {
#pragma unroll
            for (int reg = 0; reg < 4; ++reg)
                ilds[t & 1][wave][q * 4 + reg][r16] = iacc[reg];
        }
        // stage H^{t-1} (bf16) into LDS: coalesced 16B chunks
        {
            const bf16* src = hbuf + (((size_t)((t & 1) ^ 1)) * NGROUP + g) * BG * MEM;
#pragma unroll
            for (int it = 0; it < 8; ++it) {
                int fi = it * 256 + tid;
                int row = fi >> 7;
                int off = (fi & 127) * 8;
                bf16x8 v = *(const bf16x8*)(src + (size_t)row * MEM + off);
                *(bf16x8*)(&Hlds[row][off]) = v;
            }
        }
        __syncthreads();

        // m = H @ W_mm slice: wave owns (m_a|m_c) x K-half, 16 MFMAs, B from registers
        {
            f32x4 macc = {0.f, 0.f, 0.f, 0.f};
            int kh = wave & 1;
#pragma unroll
            for (int i = 0; i < 16; ++i) {
                int kb = kh * 16 + i;
                bf16x8 af = *(const bf16x8*)(&Hlds[r16][kb * 32 + q * 8]);
                macc = __builtin_amdgcn_mfma_f32_16x16x32_bf16(af, wb[i], macc, 0, 0, 0);
            }
#pragma unroll
            for (int reg = 0; reg < 4; ++reg)
                mlds[wave][q * 4 + reg][r16] = macc[reg];
        }
        __syncthreads();

        // elementwise nBRC update: one thread per (batch, col)
        {
            float ma = mlds[0][bloc][cl] + mlds[1][bloc][cl];
            float mc = mlds[2][bloc][cl] + mlds[3][bloc][cl];
            float ia = ilds[t & 1][0][bloc][cl];
            float ic = ilds[t & 1][1][bloc][cl];
            float io = ilds[t & 1][2][bloc][cl];
            float h0 = ownh[bloc][cl];
            float a = 1.f + tanhf(ia + ma);
            float c = 1.f / (1.f + expf(-(ic + mc)));
            float hn = c * h0 + (1.f - c) * tanhf(io + a * h0);
            ownh[bloc][cl] = hn;
            hbuf[(((size_t)(t & 1)) * NGROUP + g) * BG * MEM + (size_t)bloc * MEM + m * 16 + cl] = (bf16)hn;
            float v0 = hn * wa0, v1 = hn * wa1, v2 = hn * wa2;
#pragma unroll
            for (int off = 8; off >= 1; off >>= 1) {
                v0 += __shfl_xor(v0, off);
                v1 += __shfl_xor(v1, off);
                v2 += __shfl_xor(v2, off);
            }
            if (cl == 0) {
                float* dst = accout + (((size_t)t * 64) + g * 16 + bloc) * 3;
                atomicAdd(dst + 0, v0);
                atomicAdd(dst + 1, v1);
                atomicAdd(dst + 2, v2);
            }
        }
        __syncthreads();

        if (t < L_SEQ - 1) {
            // wave 3 (no i-MFMA work) arrives+spins; waves 0-2 prefetch next i-proj
            if (tid == 192) {
                __hip_atomic_fetch_add(myctr, 1u, __ATOMIC_RELEASE, __HIP_MEMORY_SCOPE_AGENT);
            }
            iacc = comp_iacc(t + 1);
            if (tid == 192) {
                unsigned int target = (unsigned int)(NMEM * (t + 1));
                while (__hip_atomic_load(myctr, __ATOMIC_RELAXED, __HIP_MEMORY_SCOPE_AGENT) < target) {
                    __builtin_amdgcn_s_sleep(8);
                    if (--spin_budget <= 0) break;
                }
                __builtin_amdgcn_fence(__ATOMIC_ACQUIRE, "agent");
            }
            __syncthreads();
        }
    }
}

// ---------------- epilogue: + b_act, softmax, f32 out ----------------
__global__ void k_final(const float* __restrict__ acc, const float* __restrict__ bact,
                        float* __restrict__ out) {
    int idx = blockIdx.x * 256 + threadIdx.x;   // idx = t*64 + b (acc layout)
    if (idx >= B_TOT * L_SEQ) return;
    int t = idx >> 6;
    int b = idx & 63;
    const float* a = acc + (size_t)idx * 3;
    float l0 = a[0] + bact[0];
    float l1 = a[1] + bact[1];
    float l2 = a[2] + bact[2];
    float mx = fmaxf(l0, fmaxf(l1, l2));
    float e0 = expf(l0 - mx), e1 = expf(l1 - mx), e2 = expf(l2 - mx);
    float inv = 1.f / (e0 + e1 + e2);
    float* o = out + ((size_t)b * L_SEQ + t) * 3;
    o[0] = e0 * inv;
    o[1] = e1 * inv;
    o[2] = e2 * inv;
}

extern "C" void kernel_launch(void* const* d_in, const int* in_sizes, int n_in,
                              void* d_out, int out_size, void* d_ws, size_t ws_size,
                              hipStream_t stream) {
    const float* x    = (const float*)d_in[0];
    const float* Ws   = (const float*)d_in[1];
    const float* bs   = (const float*)d_in[2];
    const float* Wim  = (const float*)d_in[3];
    const float* Wmm  = (const float*)d_in[4];
    const float* Wact = (const float*)d_in[5];
    const float* bact = (const float*)d_in[6];

    char* ws = (char*)d_ws;
    bf16* inputs = (bf16*)(ws + OFF_INPUTS);
    bf16* pmm    = (bf16*)(ws + OFF_WMM);
    bf16* pim    = (bf16*)(ws + OFF_WIM);
    bf16* hbuf   = (bf16*)(ws + OFF_HBUF);
    float* acc   = (float*)(ws + OFF_ACC);
    unsigned int* ctr = (unsigned int*)(ws + OFF_CTR);

    hipMemsetAsync(hbuf, 0, SZ_HBUF, stream);
    hipMemsetAsync(acc, 0, SZ_ACC, stream);
    hipMemsetAsync(ctr, 0, SZ_CTR, stream);

    k_sense<<<L_SEQ, 256, 0, stream>>>(x, Ws, bs, inputs);
    k_pack<<<(128 * 32 * 64 * 8 + 192 * 4 * 64 * 8) / 256, 256, 0, stream>>>(Wmm, Wim, pmm, pim);
    k_main<<<NGROUP * NMEM, 256, 0, stream>>>(inputs, pmm, pim, Wact, hbuf, acc, ctr);
    k_final<<<(B_TOT * L_SEQ + 255) / 256, 256, 0, stream>>>(acc, bact, (float*)d_out);
}

// Round 4
// 12739.421 us; speedup vs baseline: 1.1725x; 1.1725x over previous
//
#include <hip/hip_runtime.h>
#include <hip/hip_bf16.h>

// SenseMemAct: sense Linear -> nBRC scan (L=1024) -> actor Linear -> softmax
// f32 in / f32 out. R3 passed at 14.9ms, sync-latency-bound (MfmaUtil 0.9%).
// R4: barrier redesign — per-WG arrival slots + wave-wide ballot poll (no
// contended RMW), and NO acquire fence: H exchanged via agent-scope 8B
// atomic load/store (per-access MALL coherence) so L2 is never invalidated.

#define B_TOT 64
#define L_SEQ 1024
#define N_IN 64
#define INSZ 128
#define MEM 1024
#define DEC 3

#define NGROUP 4
#define BG 16
#define NMEM 64

typedef __hip_bfloat16 bf16;
typedef short bf16x8 __attribute__((ext_vector_type(8)));
typedef float f32x4 __attribute__((ext_vector_type(4)));
typedef unsigned long long ull;

// ---- workspace layout (bytes) ----
#define OFF_INPUTS 0
#define SZ_INPUTS  (L_SEQ * 64 * INSZ * 2)                 // 16 MB (bf16)
#define OFF_WMM    (OFF_INPUTS + SZ_INPUTS)
#define SZ_WMM     (128 * 32 * 64 * 8 * 2)                 // 4 MB
#define OFF_WIM    (OFF_WMM + SZ_WMM)
#define SZ_WIM     (192 * 4 * 64 * 8 * 2)                  // 0.75 MB
#define OFF_HBUF   (OFF_WIM + SZ_WIM)
#define SZ_HBUF    (2 * NGROUP * BG * MEM * 2)             // 256 KB
#define OFF_ACC    (OFF_HBUF + SZ_HBUF)
#define SZ_ACC     (L_SEQ * B_TOT * DEC * 4)               // 768 KB
#define OFF_CTR    (OFF_ACC + SZ_ACC)
#define SZ_CTR     (NGROUP * 64 * 4)                       // arrival slots

// ---------------- sense: inputs = x @ W_sense + b_sense ----------------
__global__ void k_sense(const float* __restrict__ x, const float* __restrict__ Ws,
                        const float* __restrict__ bs, bf16* __restrict__ inputs) {
    int t = blockIdx.x;
    int tid = threadIdx.x;
    __shared__ float xls[64][64];
    __shared__ float wls[64][128];
    for (int idx = tid; idx < 64 * 64; idx += 256) {
        int b = idx >> 6, k = idx & 63;
        xls[b][k] = x[((size_t)b * L_SEQ + t) * N_IN + k];
    }
    for (int idx = tid; idx < 64 * 128; idx += 256) {
        int k = idx >> 7, j = idx & 127;
        wls[k][j] = Ws[k * INSZ + j];
    }
    __syncthreads();
    int j = tid & 127;
    int bh = tid >> 7;
    float bj = bs[j];
    for (int bi = 0; bi < 32; ++bi) {
        int b = bh * 32 + bi;
        float acc = bj;
#pragma unroll
        for (int k = 0; k < 64; ++k) acc += xls[b][k] * wls[k][j];
        inputs[((size_t)t * 64 + b) * INSZ + j] = (bf16)acc;
    }
}

// ---------------- pack weights into bf16 MFMA B-fragment order ----------------
// frag element (ct, kb, lane, j): n = ct*16 + (lane&15); k = kb*32 + (lane>>4)*8 + j
__global__ void k_pack(const float* __restrict__ Wmm, const float* __restrict__ Wim,
                       bf16* __restrict__ pmm, bf16* __restrict__ pim) {
    int idx = blockIdx.x * 256 + threadIdx.x;
    const int NMMF = 128 * 32 * 64 * 8;  // 2097152
    if (idx < NMMF) {
        int j = idx & 7, lane = (idx >> 3) & 63, kb = (idx >> 9) & 31, ct = idx >> 14;
        int n = ct * 16 + (lane & 15);
        int k = kb * 32 + ((lane >> 4) << 3) + j;
        pmm[idx] = (bf16)Wmm[(size_t)k * 2048 + n];
    } else {
        int idx2 = idx - NMMF;
        if (idx2 < 192 * 4 * 64 * 8) {
            int j = idx2 & 7, lane = (idx2 >> 3) & 63, kb = (idx2 >> 9) & 3, ct = idx2 >> 11;
            int n = ct * 16 + (lane & 15);
            int k = kb * 32 + ((lane >> 4) << 3) + j;
            pim[idx2] = (bf16)Wim[(size_t)k * 3072 + n];
        }
    }
}

// ---------------- persistent recurrent kernel ----------------
__launch_bounds__(256, 1)
__global__ void k_main(const bf16* __restrict__ inputs, const bf16* __restrict__ pmm,
                       const bf16* __restrict__ pim, const float* __restrict__ Wact,
                       bf16* __restrict__ hbuf, float* __restrict__ accout,
                       unsigned int* __restrict__ ctr) {
    const int g = blockIdx.x & 3;       // group (16 batches)
    const int m = blockIdx.x >> 2;      // member (16 h-cols)
    const int tid = (int)threadIdx.x;
    const int wave = tid >> 6;
    const int lane = tid & 63;
    const int r16 = lane & 15;          // A-row / B-col within tile
    const int q = lane >> 4;            // quad
    const int cl = tid & 15;            // elementwise local col
    const int bloc = tid >> 4;          // elementwise local batch

    __shared__ bf16 Hlds[16][1032];     // stride 1032 elems (16B-aligned, odd x16)
    __shared__ float ilds[2][3][16][16];
    __shared__ float mlds[4][16][16];
    __shared__ float ownh[16][16];
    __shared__ bf16 hstage[16][16];

    // register-resident W_mm fragments: waves 0,1 -> ct=m (m_a); waves 2,3 -> ct=64+m (m_c)
    bf16x8 wb[16];
    {
        int ct = (wave < 2) ? m : 64 + m;
        int kh = wave & 1;
#pragma unroll
        for (int i = 0; i < 16; ++i) {
            int kb = kh * 16 + i;
            wb[i] = *(const bf16x8*)(pmm + (((size_t)ct * 32 + kb) * 64 + lane) * 8);
        }
    }
    // W_im fragments: wave w in {0,1,2} handles i_a / i_c / i_o  (ct2 = w*64 + m)
    bf16x8 wi[4];
    if (wave < 3) {
        int ct2 = wave * 64 + m;
#pragma unroll
        for (int kb2 = 0; kb2 < 4; ++kb2)
            wi[kb2] = *(const bf16x8*)(pim + (((size_t)ct2 * 4 + kb2) * 64 + lane) * 8);
    }
    // actor weights for this thread's h-column (f32)
    float wa0, wa1, wa2;
    {
        int col = m * 16 + cl;
        wa0 = Wact[col * 3 + 0];
        wa1 = Wact[col * 3 + 1];
        wa2 = Wact[col * 3 + 2];
    }
    ownh[bloc][cl] = 0.f;

    auto comp_iacc = [&](int t) -> f32x4 {
        f32x4 a = {0.f, 0.f, 0.f, 0.f};
        if (wave < 3) {
#pragma unroll
            for (int kb2 = 0; kb2 < 4; ++kb2) {
                bf16x8 af = *(const bf16x8*)(inputs +
                    ((size_t)t * 64 + g * 16 + r16) * INSZ + kb2 * 32 + q * 8);
                a = __builtin_amdgcn_mfma_f32_16x16x32_bf16(af, wi[kb2], a, 0, 0, 0);
            }
        }
        return a;
    };

    f32x4 iacc = comp_iacc(0);
    unsigned int* slots = ctr + g * 64;   // per-WG arrival slots
    int spin_budget = 1 << 22;            // wrong-answer instead of hang on bug

#pragma clang loop unroll(disable)
    for (int t = 0; t < L_SEQ; ++t) {
        // deposit this step's input-projection tiles
        if (wave < 3) {
#pragma unroll
            for (int reg = 0; reg < 4; ++reg)
                ilds[t & 1][wave][q * 4 + reg][r16] = iacc[reg];
        }
        // stage H^{t-1} into LDS via agent-scope 8B loads (MALL-coherent, no fence)
        {
            const ull* src = (const ull*)(hbuf +
                (((size_t)((t & 1) ^ 1)) * NGROUP + g) * BG * MEM);
            ull tmp[16];
#pragma unroll
            for (int it = 0; it < 16; ++it) {
                int fi = it * 256 + tid;   // 0..4095 (4096 ull = 32 KB)
                tmp[it] = __hip_atomic_load(src + fi, __ATOMIC_RELAXED,
                                            __HIP_MEMORY_SCOPE_AGENT);
            }
#pragma unroll
            for (int it = 0; it < 16; ++it) {
                int fi = it * 256 + tid;
                int row = fi >> 8;              // 256 ull per 1024-col row
                int off = (fi & 255) * 4;       // bf16 elems
                *(ull*)(&Hlds[row][off]) = tmp[it];
            }
        }
        __syncthreads();

        // m = H @ W_mm slice: wave owns (m_a|m_c) x K-half, 16 MFMAs, B from registers
        {
            f32x4 macc = {0.f, 0.f, 0.f, 0.f};
            int kh = wave & 1;
#pragma unroll
            for (int i = 0; i < 16; ++i) {
                int kb = kh * 16 + i;
                bf16x8 af = *(const bf16x8*)(&Hlds[r16][kb * 32 + q * 8]);
                macc = __builtin_amdgcn_mfma_f32_16x16x32_bf16(af, wb[i], macc, 0, 0, 0);
            }
#pragma unroll
            for (int reg = 0; reg < 4; ++reg)
                mlds[wave][q * 4 + reg][r16] = macc[reg];
        }
        __syncthreads();

        // elementwise nBRC update: one thread per (batch, col)
        {
            float ma = mlds[0][bloc][cl] + mlds[1][bloc][cl];
            float mc = mlds[2][bloc][cl] + mlds[3][bloc][cl];
            float ia = ilds[t & 1][0][bloc][cl];
            float ic = ilds[t & 1][1][bloc][cl];
            float io = ilds[t & 1][2][bloc][cl];
            float h0 = ownh[bloc][cl];
            float a = 1.f + tanhf(ia + ma);
            float c = 1.f / (1.f + expf(-(ic + mc)));
            float hn = c * h0 + (1.f - c) * tanhf(io + a * h0);
            ownh[bloc][cl] = hn;
            hstage[bloc][cl] = (bf16)hn;
            float v0 = hn * wa0, v1 = hn * wa1, v2 = hn * wa2;
#pragma unroll
            for (int off = 8; off >= 1; off >>= 1) {
                v0 += __shfl_xor(v0, off);
                v1 += __shfl_xor(v1, off);
                v2 += __shfl_xor(v2, off);
            }
            if (cl == 0) {
                float* dst = accout + (((size_t)t * 64) + g * 16 + bloc) * 3;
                atomicAdd(dst + 0, v0);
                atomicAdd(dst + 1, v1);
                atomicAdd(dst + 2, v2);
            }
        }
        __syncthreads();

        if (t < L_SEQ - 1) {
            // publish H^t: 64 threads x 8B agent-scope stores (write-through to MALL)
            if (tid < 64) {
                int row = tid >> 2, chunk = tid & 3;
                ull v = *(const ull*)(&hstage[row][chunk * 4]);
                ull* dst = (ull*)(hbuf + (((size_t)(t & 1)) * NGROUP + g) * BG * MEM +
                                  (size_t)row * MEM + m * 16) + chunk;
                __hip_atomic_store(dst, v, __ATOMIC_RELAXED, __HIP_MEMORY_SCOPE_AGENT);
            }
            __syncthreads();   // drains vmcnt: all H stores acked at MALL

            // arrival: one release store to our own slot (no contended RMW)
            if (tid == 0)
                __hip_atomic_store(&slots[m], (unsigned)(t + 1), __ATOMIC_RELEASE,
                                   __HIP_MEMORY_SCOPE_AGENT);

            // waves 0-2 prefetch next i-proj while wave 3 polls all 64 slots
            iacc = comp_iacc(t + 1);
            if (wave == 3) {
                bool done = false;
                while (!done && --spin_budget > 0) {
                    unsigned v = __hip_atomic_load(&slots[lane], __ATOMIC_RELAXED,
                                                   __HIP_MEMORY_SCOPE_AGENT);
                    done = (bool)__all((int)(v >= (unsigned)(t + 1)));
                }
            }
            __syncthreads();
        }
    }
}

// ---------------- epilogue: + b_act, softmax, f32 out ----------------
__global__ void k_final(const float* __restrict__ acc, const float* __restrict__ bact,
                        float* __restrict__ out) {
    int idx = blockIdx.x * 256 + threadIdx.x;   // idx = t*64 + b (acc layout)
    if (idx >= B_TOT * L_SEQ) return;
    int t = idx >> 6;
    int b = idx & 63;
    const float* a = acc + (size_t)idx * 3;
    float l0 = a[0] + bact[0];
    float l1 = a[1] + bact[1];
    float l2 = a[2] + bact[2];
    float mx = fmaxf(l0, fmaxf(l1, l2));
    float e0 = expf(l0 - mx), e1 = expf(l1 - mx), e2 = expf(l2 - mx);
    float inv = 1.f / (e0 + e1 + e2);
    float* o = out + ((size_t)b * L_SEQ + t) * 3;
    o[0] = e0 * inv;
    o[1] = e1 * inv;
    o[2] = e2 * inv;
}

extern "C" void kernel_launch(void* const* d_in, const int* in_sizes, int n_in,
                              void* d_out, int out_size, void* d_ws, size_t ws_size,
                              hipStream_t stream) {
    const float* x    = (const float*)d_in[0];
    const float* Ws   = (const float*)d_in[1];
    const float* bs   = (const float*)d_in[2];
    const float* Wim  = (const float*)d_in[3];
    const float* Wmm  = (const float*)d_in[4];
    const float* Wact = (const float*)d_in[5];
    const float* bact = (const float*)d_in[6];

    char* ws = (char*)d_ws;
    bf16* inputs = (bf16*)(ws + OFF_INPUTS);
    bf16* pmm    = (bf16*)(ws + OFF_WMM);
    bf16* pim    = (bf16*)(ws + OFF_WIM);
    bf16* hbuf   = (bf16*)(ws + OFF_HBUF);
    float* acc   = (float*)(ws + OFF_ACC);
    unsigned int* ctr = (unsigned int*)(ws + OFF_CTR);

    hipMemsetAsync(hbuf, 0, SZ_HBUF, stream);
    hipMemsetAsync(acc, 0, SZ_ACC, stream);
    hipMemsetAsync(ctr, 0, SZ_CTR, stream);

    k_sense<<<L_SEQ, 256, 0, stream>>>(x, Ws, bs, inputs);
    k_pack<<<(128 * 32 * 64 * 8 + 192 * 4 * 64 * 8) / 256, 256, 0, stream>>>(Wmm, Wim, pmm, pim);
    k_main<<<NGROUP * NMEM, 256, 0, stream>>>(inputs, pmm, pim, Wact, hbuf, acc, ctr);
    k_final<<<(B_TOT * L_SEQ + 255) / 256, 256, 0, stream>>>(acc, bact, (float*)d_out);
}

// Round 5
// 4261.262 us; speedup vs baseline: 3.5054x; 2.9896x over previous
//
#include <hip/hip_runtime.h>
#include <hip/hip_bf16.h>

// SenseMemAct: sense Linear -> nBRC scan (L=1024) -> actor Linear -> softmax
// f32 in / f32 out. R4: 12.7ms, latency-bound (MfmaUtil 1.0%).
// R5: (a) actor logits computed in-WG from the already-staged Hlds (one step
// late) -> kills the per-step 64-way atomicAdd storm AND the k_final pass;
// (b) arrival = relaxed flag after explicit in-wave s_waitcnt vmcnt(0) -> no
// RELEASE (no wbl2) per step; (c) fast __expf-based tanh/sigmoid.

#define B_TOT 64
#define L_SEQ 1024
#define N_IN 64
#define INSZ 128
#define MEM 1024
#define DEC 3

#define NGROUP 4
#define BG 16
#define NMEM 64

typedef __hip_bfloat16 bf16;
typedef short bf16x8 __attribute__((ext_vector_type(8)));
typedef float f32x4 __attribute__((ext_vector_type(4)));
typedef unsigned long long ull;

// ---- workspace layout (bytes) ----
#define OFF_INPUTS 0
#define SZ_INPUTS  (L_SEQ * 64 * INSZ * 2)                 // 16 MB (bf16)
#define OFF_WMM    (OFF_INPUTS + SZ_INPUTS)
#define SZ_WMM     (128 * 32 * 64 * 8 * 2)                 // 4 MB
#define OFF_WIM    (OFF_WMM + SZ_WMM)
#define SZ_WIM     (192 * 4 * 64 * 8 * 2)                  // 0.75 MB
#define OFF_HBUF   (OFF_WIM + SZ_WIM)
#define SZ_HBUF    (2 * NGROUP * BG * MEM * 2)             // 256 KB
#define OFF_CTR    (OFF_HBUF + SZ_HBUF)
#define SZ_CTR     (NGROUP * 64 * 4)                       // arrival slots

__device__ __forceinline__ float fast_tanh(float x) {
    float e = __expf(2.f * x);
    return 1.f - 2.f / (e + 1.f);
}
__device__ __forceinline__ float fast_sigmoid(float x) {
    return 1.f / (1.f + __expf(-x));
}

// ---------------- sense: inputs = x @ W_sense + b_sense ----------------
__global__ void k_sense(const float* __restrict__ x, const float* __restrict__ Ws,
                        const float* __restrict__ bs, bf16* __restrict__ inputs) {
    int t = blockIdx.x;
    int tid = threadIdx.x;
    __shared__ float xls[64][64];
    __shared__ float wls[64][128];
    for (int idx = tid; idx < 64 * 64; idx += 256) {
        int b = idx >> 6, k = idx & 63;
        xls[b][k] = x[((size_t)b * L_SEQ + t) * N_IN + k];
    }
    for (int idx = tid; idx < 64 * 128; idx += 256) {
        int k = idx >> 7, j = idx & 127;
        wls[k][j] = Ws[k * INSZ + j];
    }
    __syncthreads();
    int j = tid & 127;
    int bh = tid >> 7;
    float bj = bs[j];
    for (int bi = 0; bi < 32; ++bi) {
        int b = bh * 32 + bi;
        float acc = bj;
#pragma unroll
        for (int k = 0; k < 64; ++k) acc += xls[b][k] * wls[k][j];
        inputs[((size_t)t * 64 + b) * INSZ + j] = (bf16)acc;
    }
}

// ---------------- pack weights into bf16 MFMA B-fragment order ----------------
// frag element (ct, kb, lane, j): n = ct*16 + (lane&15); k = kb*32 + (lane>>4)*8 + j
__global__ void k_pack(const float* __restrict__ Wmm, const float* __restrict__ Wim,
                       bf16* __restrict__ pmm, bf16* __restrict__ pim) {
    int idx = blockIdx.x * 256 + threadIdx.x;
    const int NMMF = 128 * 32 * 64 * 8;  // 2097152
    if (idx < NMMF) {
        int j = idx & 7, lane = (idx >> 3) & 63, kb = (idx >> 9) & 31, ct = idx >> 14;
        int n = ct * 16 + (lane & 15);
        int k = kb * 32 + ((lane >> 4) << 3) + j;
        pmm[idx] = (bf16)Wmm[(size_t)k * 2048 + n];
    } else {
        int idx2 = idx - NMMF;
        if (idx2 < 192 * 4 * 64 * 8) {
            int j = idx2 & 7, lane = (idx2 >> 3) & 63, kb = (idx2 >> 9) & 3, ct = idx2 >> 11;
            int n = ct * 16 + (lane & 15);
            int k = kb * 32 + ((lane >> 4) << 3) + j;
            pim[idx2] = (bf16)Wim[(size_t)k * 3072 + n];
        }
    }
}

// ---------------- persistent recurrent kernel ----------------
__launch_bounds__(256, 1)
__global__ void k_main(const bf16* __restrict__ inputs, const bf16* __restrict__ pmm,
                       const bf16* __restrict__ pim, const float* __restrict__ Wact,
                       const float* __restrict__ bact, bf16* __restrict__ hbuf,
                       float* __restrict__ out, unsigned int* __restrict__ ctr) {
    const int g = blockIdx.x & 3;       // group (16 batches)
    const int m = blockIdx.x >> 2;      // member (16 h-cols)
    const int tid = (int)threadIdx.x;
    const int wave = tid >> 6;
    const int lane = tid & 63;
    const int r16 = lane & 15;          // A-row / B-col within tile
    const int q = lane >> 4;            // quad
    const int cl = tid & 15;            // elementwise local col
    const int bloc = tid >> 4;          // elementwise local batch

    __shared__ bf16 Hlds[16][1032];     // stride 1032 elems (16B-aligned, odd x16)
    __shared__ float ilds[2][3][16][16];
    __shared__ float mlds[4][16][16];
    __shared__ float ownh[16][16];
    __shared__ bf16 hstage[16][16];
    __shared__ float wact_lds[1024 * 3];
    __shared__ float aplds[4][3];
    __shared__ float bactl[3];

    // stage actor weights (f32) into LDS once
    for (int idx = tid; idx < 1024 * 3; idx += 256) wact_lds[idx] = Wact[idx];
    if (tid < 3) bactl[tid] = bact[tid];

    // register-resident W_mm fragments: waves 0,1 -> ct=m (m_a); waves 2,3 -> ct=64+m (m_c)
    bf16x8 wb[16];
    {
        int ct = (wave < 2) ? m : 64 + m;
        int kh = wave & 1;
#pragma unroll
        for (int i = 0; i < 16; ++i) {
            int kb = kh * 16 + i;
            wb[i] = *(const bf16x8*)(pmm + (((size_t)ct * 32 + kb) * 64 + lane) * 8);
        }
    }
    // W_im fragments: wave w in {0,1,2} handles i_a / i_c / i_o  (ct2 = w*64 + m)
    bf16x8 wi[4];
    if (wave < 3) {
        int ct2 = wave * 64 + m;
#pragma unroll
        for (int kb2 = 0; kb2 < 4; ++kb2)
            wi[kb2] = *(const bf16x8*)(pim + (((size_t)ct2 * 4 + kb2) * 64 + lane) * 8);
    }
    ownh[bloc][cl] = 0.f;

    auto comp_iacc = [&](int t) -> f32x4 {
        f32x4 a = {0.f, 0.f, 0.f, 0.f};
        if (wave < 3) {
#pragma unroll
            for (int kb2 = 0; kb2 < 4; ++kb2) {
                bf16x8 af = *(const bf16x8*)(inputs +
                    ((size_t)t * 64 + g * 16 + r16) * INSZ + kb2 * 32 + q * 8);
                a = __builtin_amdgcn_mfma_f32_16x16x32_bf16(af, wi[kb2], a, 0, 0, 0);
            }
        }
        return a;
    };

    // actor partial: thread covers 4 cols of Hlds[hrow]; wave-reduce; leaders -> aplds
    auto actor_emit = [&](int hrow) {
        float p0 = 0.f, p1 = 0.f, p2 = 0.f;
        int c0 = tid * 4;
        const bf16* hp = &Hlds[hrow][c0];
#pragma unroll
        for (int i = 0; i < 4; ++i) {
            float hv = (float)hp[i];
            p0 += hv * wact_lds[(c0 + i) * 3 + 0];
            p1 += hv * wact_lds[(c0 + i) * 3 + 1];
            p2 += hv * wact_lds[(c0 + i) * 3 + 2];
        }
#pragma unroll
        for (int off = 32; off >= 1; off >>= 1) {
            p0 += __shfl_xor(p0, off);
            p1 += __shfl_xor(p1, off);
            p2 += __shfl_xor(p2, off);
        }
        if (lane == 0) { aplds[wave][0] = p0; aplds[wave][1] = p1; aplds[wave][2] = p2; }
    };
    auto actor_fin = [&](int tout) {   // tid==0 only; after a barrier following emit
        float l0 = aplds[0][0] + aplds[1][0] + aplds[2][0] + aplds[3][0] + bactl[0];
        float l1 = aplds[0][1] + aplds[1][1] + aplds[2][1] + aplds[3][1] + bactl[1];
        float l2 = aplds[0][2] + aplds[1][2] + aplds[2][2] + aplds[3][2] + bactl[2];
        float mx = fmaxf(l0, fmaxf(l1, l2));
        float e0 = __expf(l0 - mx), e1 = __expf(l1 - mx), e2 = __expf(l2 - mx);
        float inv = 1.f / (e0 + e1 + e2);
        float* o = out + ((size_t)(g * 16 + m) * L_SEQ + tout) * 3;
        o[0] = e0 * inv; o[1] = e1 * inv; o[2] = e2 * inv;
    };

    f32x4 iacc = comp_iacc(0);
    unsigned int* slots = ctr + g * 64;   // per-WG arrival slots
    int spin_budget = 1 << 23;            // wrong-answer instead of hang on bug

#pragma clang loop unroll(disable)
    for (int t = 0; t < L_SEQ; ++t) {
        // deposit this step's input-projection tiles
        if (wave < 3) {
#pragma unroll
            for (int reg = 0; reg < 4; ++reg)
                ilds[t & 1][wave][q * 4 + reg][r16] = iacc[reg];
        }
        // stage H^{t-1} into LDS via agent-scope 8B loads (MALL-coherent)
        {
            const ull* src = (const ull*)(hbuf +
                (((size_t)((t & 1) ^ 1)) * NGROUP + g) * BG * MEM);
            ull tmp[16];
#pragma unroll
            for (int it = 0; it < 16; ++it) {
                int fi = it * 256 + tid;
                tmp[it] = __hip_atomic_load(src + fi, __ATOMIC_RELAXED,
                                            __HIP_MEMORY_SCOPE_AGENT);
            }
#pragma unroll
            for (int it = 0; it < 16; ++it) {
                int fi = it * 256 + tid;
                int row = fi >> 8;
                int off = (fi & 255) * 4;
                *(ull*)(&Hlds[row][off]) = tmp[it];
            }
        }
        __syncthreads();

        // m = H @ W_mm slice: wave owns (m_a|m_c) x K-half, 16 MFMAs, B from registers
        {
            f32x4 macc = {0.f, 0.f, 0.f, 0.f};
            int kh = wave & 1;
#pragma unroll
            for (int i = 0; i < 16; ++i) {
                int kb = kh * 16 + i;
                bf16x8 af = *(const bf16x8*)(&Hlds[r16][kb * 32 + q * 8]);
                macc = __builtin_amdgcn_mfma_f32_16x16x32_bf16(af, wb[i], macc, 0, 0, 0);
            }
#pragma unroll
            for (int reg = 0; reg < 4; ++reg)
                mlds[wave][q * 4 + reg][r16] = macc[reg];
        }
        // actor partials for logits[t-1] of batch g*16+m (members m<16 only)
        if (m < 16 && t > 0) actor_emit(m);
        __syncthreads();

        // elementwise nBRC update: one thread per (batch, col)
        {
            float ma = mlds[0][bloc][cl] + mlds[1][bloc][cl];
            float mc = mlds[2][bloc][cl] + mlds[3][bloc][cl];
            float ia = ilds[t & 1][0][bloc][cl];
            float ic = ilds[t & 1][1][bloc][cl];
            float io = ilds[t & 1][2][bloc][cl];
            float h0 = ownh[bloc][cl];
            float a = 1.f + fast_tanh(ia + ma);
            float c = fast_sigmoid(ic + mc);
            float hn = c * h0 + (1.f - c) * fast_tanh(io + a * h0);
            ownh[bloc][cl] = hn;
            hstage[bloc][cl] = (bf16)hn;
        }
        __syncthreads();   // hstage complete; aplds complete

        // actor finish + output store (one thread; drained with publish below)
        if (m < 16 && t > 0 && tid == 0) actor_fin(t - 1);

        // publish H^t: wave 0 does 8B agent-scope stores, in-wave drain, flag
        if (tid < 64) {
            int row = tid >> 2, chunk = tid & 3;
            ull v = *(const ull*)(&hstage[row][chunk * 4]);
            ull* dst = (ull*)(hbuf + (((size_t)(t & 1)) * NGROUP + g) * BG * MEM +
                              (size_t)row * MEM + m * 16) + chunk;
            __hip_atomic_store(dst, v, __ATOMIC_RELAXED, __HIP_MEMORY_SCOPE_AGENT);
            asm volatile("s_waitcnt vmcnt(0)" ::: "memory");   // H (and out) acked at MALL
            if (tid == 0)
                __hip_atomic_store(&slots[m], (unsigned)(t + 1), __ATOMIC_RELAXED,
                                   __HIP_MEMORY_SCOPE_AGENT);
        }

        // waves 0-2 prefetch next i-proj while wave 3 polls all 64 slots
        if (t + 1 < L_SEQ) iacc = comp_iacc(t + 1);
        if (wave == 3) {
            bool done = false;
            while (!done && --spin_budget > 0) {
                unsigned v = __hip_atomic_load(&slots[lane], __ATOMIC_RELAXED,
                                               __HIP_MEMORY_SCOPE_AGENT);
                done = (bool)__all((int)(v >= (unsigned)(t + 1)));
            }
        }
        __syncthreads();
    }

    // epilogue: logits/softmax for t = L-1 (H^{L-1} published in buf (L-1)&1 = 1)
    if (m < 16) {
        const ull* src = (const ull*)(hbuf + ((size_t)1 * NGROUP + g) * BG * MEM +
                                      (size_t)m * MEM);
        ull hv = __hip_atomic_load(src + tid, __ATOMIC_RELAXED, __HIP_MEMORY_SCOPE_AGENT);
        *(ull*)(&Hlds[0][tid * 4]) = hv;
        __syncthreads();
        actor_emit(0);
        __syncthreads();
        if (tid == 0) actor_fin(L_SEQ - 1);
    }
}

extern "C" void kernel_launch(void* const* d_in, const int* in_sizes, int n_in,
                              void* d_out, int out_size, void* d_ws, size_t ws_size,
                              hipStream_t stream) {
    const float* x    = (const float*)d_in[0];
    const float* Ws   = (const float*)d_in[1];
    const float* bs   = (const float*)d_in[2];
    const float* Wim  = (const float*)d_in[3];
    const float* Wmm  = (const float*)d_in[4];
    const float* Wact = (const float*)d_in[5];
    const float* bact = (const float*)d_in[6];

    char* ws = (char*)d_ws;
    bf16* inputs = (bf16*)(ws + OFF_INPUTS);
    bf16* pmm    = (bf16*)(ws + OFF_WMM);
    bf16* pim    = (bf16*)(ws + OFF_WIM);
    bf16* hbuf   = (bf16*)(ws + OFF_HBUF);
    unsigned int* ctr = (unsigned int*)(ws + OFF_CTR);

    hipMemsetAsync(hbuf, 0, SZ_HBUF, stream);
    hipMemsetAsync(ctr, 0, SZ_CTR, stream);

    k_sense<<<L_SEQ, 256, 0, stream>>>(x, Ws, bs, inputs);
    k_pack<<<(128 * 32 * 64 * 8 + 192 * 4 * 64 * 8) / 256, 256, 0, stream>>>(Wmm, Wim, pmm, pim);
    k_main<<<NGROUP * NMEM, 256, 0, stream>>>(inputs, pmm, pim, Wact, bact, hbuf,
                                              (float*)d_out, ctr);
}